// Round 4
// baseline (343.529 us; speedup 1.0000x reference)
//
#include <hip/hip_runtime.h>
#include <stdint.h>

typedef unsigned int u32;
typedef unsigned long long u64;

#define NTOT 21824   // 128*128 + 64*64 + 32*32 + 16*16 + 8*8
#define NBATCH 16
#define TOPN 1000
#define MAXOBJ 100
#define CAP 2048     // refine until candidate count <= CAP
#define CAPC 8192    // global candidate buffer capacity per batch

// -------------------------------------------------------------------------
// Stage 0: zero hist0 (16*2048 u32) + gcnt (16 u32), contiguous.
// -------------------------------------------------------------------------
__global__ void zero_kernel(u32* __restrict__ h) {
    int i = blockIdx.x * 1024 + threadIdx.x;
    if (i < NBATCH * 2048 + NBATCH) h[i] = 0;
}

// -------------------------------------------------------------------------
// Stage 1: decode + fused per-batch 11-bit key histogram.
// -------------------------------------------------------------------------
__global__ __launch_bounds__(256) void decode_kernel(
    const float* __restrict__ cls0, const float* __restrict__ cls1,
    const float* __restrict__ cls2, const float* __restrict__ cls3,
    const float* __restrict__ cls4,
    const float* __restrict__ reg0, const float* __restrict__ reg1,
    const float* __restrict__ reg2, const float* __restrict__ reg3,
    const float* __restrict__ reg4,
    const float* __restrict__ ctr0, const float* __restrict__ ctr1,
    const float* __restrict__ ctr2, const float* __restrict__ ctr3,
    const float* __restrict__ ctr4,
    u32* __restrict__ keys, int* __restrict__ clsidx, float4* __restrict__ boxes,
    u32* __restrict__ hist0)
{
    __shared__ u32 bh[2048];
    for (int i = threadIdx.x; i < 2048; i += 256) bh[i] = 0;
    __syncthreads();

    int loc = blockIdx.x * 256 + threadIdx.x;
    int b = blockIdx.y;
    if (loc < NTOT) {
        const float *cp, *rp, *tp;
        int li, wsh; float st;
        if (loc < 16384)      { li = loc;         wsh = 7; st = 8.f;   size_t o = (size_t)b*16384 + li; cp = cls0 + o*80; rp = reg0 + o*4; tp = ctr0 + o; }
        else if (loc < 20480) { li = loc - 16384; wsh = 6; st = 16.f;  size_t o = (size_t)b*4096  + li; cp = cls1 + o*80; rp = reg1 + o*4; tp = ctr1 + o; }
        else if (loc < 21504) { li = loc - 20480; wsh = 5; st = 32.f;  size_t o = (size_t)b*1024  + li; cp = cls2 + o*80; rp = reg2 + o*4; tp = ctr2 + o; }
        else if (loc < 21760) { li = loc - 21504; wsh = 4; st = 64.f;  size_t o = (size_t)b*256   + li; cp = cls3 + o*80; rp = reg3 + o*4; tp = ctr3 + o; }
        else                  { li = loc - 21760; wsh = 3; st = 128.f; size_t o = (size_t)b*64    + li; cp = cls4 + o*80; rp = reg4 + o*4; tp = ctr4 + o; }
        int wx = li & ((1 << wsh) - 1);
        int hy = li >> wsh;
        float px = ((float)wx + 0.5f) * st;
        float py = ((float)hy + 0.5f) * st;

        const float4* c4 = (const float4*)cp;
        float maxv = -1.0f; int arg = 0;
#pragma unroll
        for (int q = 0; q < 20; ++q) {
            float4 v = c4[q];
            if (v.x > maxv) { maxv = v.x; arg = 4*q;     }
            if (v.y > maxv) { maxv = v.y; arg = 4*q + 1; }
            if (v.z > maxv) { maxv = v.z; arg = 4*q + 2; }
            if (v.w > maxv) { maxv = v.w; arg = 4*q + 3; }
        }
        float ctr = *tp;
        float score = sqrtf(maxv * ctr);       // correctly-rounded fp32 sqrt
        float4 r = *(const float4*)rp;
        float4 bx;
        bx.x = truncf(px - r.x); bx.y = truncf(py - r.y);
        bx.z = truncf(px + r.z); bx.w = truncf(py + r.w);
        size_t o = (size_t)b * NTOT + loc;
        u32 key = (score > 0.05f) ? (__float_as_uint(score) | 0x80000000u) : 0u;
        keys[o] = key;
        clsidx[o] = arg;
        boxes[o] = bx;
        if (key) atomicAdd(&bh[key >> 21], 1u);
    }
    __syncthreads();
    for (int i = threadIdx.x; i < 2048; i += 256) {
        u32 c = bh[i];
        if (c) atomicAdd(&hist0[b * 2048 + i], c);
    }
}

// -------------------------------------------------------------------------
// Stage 2a: exact pivot P per batch via radix refinement (1 block/batch).
// Also writes output defaults.  params[b] = {P, target}.
// -------------------------------------------------------------------------
__global__ __launch_bounds__(1024) void pivot_kernel(
    const u32* __restrict__ keys, const u32* __restrict__ hist0,
    u32* __restrict__ params,
    float* __restrict__ tscore, float* __restrict__ tcls, float4* __restrict__ tbox)
{
    __shared__ u32 shist[2048];
    __shared__ u32 s_wtot[16];
    __shared__ int s_tf;
    __shared__ u32 s_C, s_above;
    int b = blockIdx.x, tid = threadIdx.x;
    int lane = tid & 63, wave = tid >> 6;
    const u32* kb = keys + (size_t)b * NTOT;

    // defaults for outputs
    for (int i = tid; i < TOPN; i += 1024) {
        size_t o = (size_t)b * TOPN + i;
        tscore[o] = -1.0f; tcls[o] = -1.0f;
        tbox[o] = make_float4(0.f, 0.f, 0.f, 0.f);
    }

    // ---- level 1: suffix scan of hist0 ----
    u32 h0 = hist0[b * 2048 + 2 * tid];
    u32 h1 = hist0[b * 2048 + 2 * tid + 1];
    if (tid == 0) s_tf = -1;
    u32 x = h0 + h1;
#pragma unroll
    for (int off = 1; off < 64; off <<= 1) {
        u32 y = __shfl_down(x, off);
        if (lane + off < 64) x += y;
    }
    if (lane == 0) s_wtot[wave] = x;
    __syncthreads();
    u32 wsuf = 0, tot = 0;
    for (int w2 = 0; w2 < 16; ++w2) { u32 v = s_wtot[w2]; tot += v; if (w2 > wave) wsuf += v; }
    u32 suf0 = x + wsuf, suf1 = suf0 - h0;
    u32 target = (tot < TOPN) ? tot : TOPN;

    if (target > 0) {
        if (suf0 >= target) atomicMax(&s_tf, 2 * tid);
        if (suf1 >= target) atomicMax(&s_tf, 2 * tid + 1);
    }
    __syncthreads();
    int t0 = s_tf;
    if (target > 0) {
        if (2 * tid == t0)     { s_C = suf0; s_above = suf0 - h0; }
        if (2 * tid + 1 == t0) { s_C = suf1; s_above = suf1 - h1; }
    }
    __syncthreads();
    u32 C0 = (target > 0) ? s_C : 0;
    u32 above0 = (target > 0) ? s_above : 0;

    // ---- level 2 (scan keys in bin t0) ----
    bool need2 = (target > 0 && C0 > CAP);
    int t1 = 0; u32 C1 = 0, above1 = 0;
    shist[2 * tid] = 0; shist[2 * tid + 1] = 0;
    if (tid == 0) s_tf = -1;
    __syncthreads();
    if (need2) {
        for (int i = tid; i < NTOT; i += 1024) {
            u32 k = kb[i];
            if (k && (int)(k >> 21) == t0) atomicAdd(&shist[(k >> 10) & 2047], 1u);
        }
    }
    __syncthreads();
    {
        u32 g0 = shist[2 * tid], g1 = shist[2 * tid + 1];
        u32 x2 = g0 + g1;
#pragma unroll
        for (int off = 1; off < 64; off <<= 1) {
            u32 y = __shfl_down(x2, off);
            if (lane + off < 64) x2 += y;
        }
        if (lane == 0) s_wtot[wave] = x2;
        __syncthreads();
        u32 ws2 = 0;
        for (int w2 = wave + 1; w2 < 16; ++w2) ws2 += s_wtot[w2];
        u32 sa0 = x2 + ws2, sa1 = sa0 - g0;
        u32 need2c = target - above0;
        if (need2) {
            if (sa0 >= need2c) atomicMax(&s_tf, 2 * tid);
            if (sa1 >= need2c) atomicMax(&s_tf, 2 * tid + 1);
        }
        __syncthreads();
        t1 = s_tf;
        if (need2) {
            if (2 * tid == t1)     { s_C = above0 + sa0; s_above = above0 + sa0 - g0; }
            if (2 * tid + 1 == t1) { s_C = above0 + sa1; s_above = above0 + sa1 - g1; }
        }
        __syncthreads();
        if (need2) { C1 = s_C; above1 = s_above; }
    }

    // ---- level 3 (scan keys in bin (t0,t1)) ----
    bool need3 = (need2 && C1 > CAP);
    int t2 = 0;
    __syncthreads();
    shist[2 * tid] = 0; shist[2 * tid + 1] = 0;
    if (tid == 0) s_tf = -1;
    __syncthreads();
    if (need3) {
        for (int i = tid; i < NTOT; i += 1024) {
            u32 k = kb[i];
            if (k && (int)(k >> 21) == t0 && (int)((k >> 10) & 2047) == t1)
                atomicAdd(&shist[k & 1023], 1u);
        }
    }
    __syncthreads();
    {
        u32 g = shist[tid];
        u32 x3 = g;
#pragma unroll
        for (int off = 1; off < 64; off <<= 1) {
            u32 y = __shfl_down(x3, off);
            if (lane + off < 64) x3 += y;
        }
        if (lane == 0) s_wtot[wave] = x3;
        __syncthreads();
        u32 ws3 = 0;
        for (int w2 = wave + 1; w2 < 16; ++w2) ws3 += s_wtot[w2];
        u32 sb = x3 + ws3;
        if (need3) {
            u32 need3c = target - above1;
            if (sb >= need3c && tid < 1024) atomicMax(&s_tf, tid);
        }
        __syncthreads();
        t2 = s_tf;
    }

    if (tid == 0) {
        u32 P;
        if (target == 0)      P = 0xFFFFFFFFu;
        else if (!need2)      P = (u32)t0 << 21;
        else if (!need3)      P = ((u32)t0 << 21) | ((u32)t1 << 10);
        else                  P = ((u32)t0 << 21) | ((u32)t1 << 10) | (u32)t2;
        params[2 * b] = P;
        params[2 * b + 1] = target;
    }
}

// -------------------------------------------------------------------------
// Stage 2b: gather all keys >= P into candbuf (ballot-compacted).
// -------------------------------------------------------------------------
__global__ __launch_bounds__(256) void gather_kernel(
    const u32* __restrict__ keys, const u32* __restrict__ params,
    u64* __restrict__ candbuf, u32* __restrict__ gcnt)
{
    int b = blockIdx.y;
    int i = blockIdx.x * 256 + threadIdx.x;
    int lane = threadIdx.x & 63;
    u32 P = params[2 * b];
    u32 k = (i < NTOT) ? keys[(size_t)b * NTOT + i] : 0u;
    bool pass = (k != 0u) && (k >= P);
    u64 mask = __ballot(pass);
    u32 cnt = (u32)__popcll(mask);
    u32 base = 0;
    if (lane == 0 && cnt) base = atomicAdd(&gcnt[b], cnt);
    base = __shfl(base, 0);
    if (pass) {
        u32 pos = base + (u32)__popcll(mask & ((1ull << lane) - 1ull));
        if (pos < CAPC)
            candbuf[(size_t)b * CAPC + pos] = ((u64)k << 32) | (u32)(~i);
    }
}

// -------------------------------------------------------------------------
// Stage 2c: rank-by-count + scatter.  Each wave owns 64 candidates; inner
// loop: coalesced 64-chunk load, then v_readlane broadcast compares (VALU,
// parallel across SIMDs -- no shared-pipe serialization).
// -------------------------------------------------------------------------
__global__ __launch_bounds__(256) void rank_kernel(
    const u64* __restrict__ candbuf, const u32* __restrict__ gcnt,
    const u32* __restrict__ params,
    const int* __restrict__ clsidx, const float4* __restrict__ boxes,
    float* __restrict__ tscore, float* __restrict__ tcls, float4* __restrict__ tbox)
{
    int b = blockIdx.y;
    int lane = threadIdx.x & 63;
    u32 M = gcnt[b]; if (M > CAPC) M = CAPC;
    u32 target = params[2 * b + 1];
    const u64* cb = candbuf + (size_t)b * CAPC;
    u32 Mr = (M + 63u) & ~63u;

    u32 wbase0 = blockIdx.x * 256 + (threadIdx.x & ~63u);
    for (u32 base = wbase0; base < M; base += 8 * 256) {   // uniform per wave
        u32 i0 = base + lane;
        bool val = (i0 < M);
        u64 e = val ? cb[i0] : ~0ull;
        u32 r = 0;
        for (u32 c0 = 0; c0 < Mr; c0 += 64) {
            u32 j = c0 + lane;
            u64 v = (j < M) ? cb[j] : 0ull;   // 0 is never > any candidate
            u32 vlo = (u32)v, vhi = (u32)(v >> 32);
#pragma unroll
            for (int s = 0; s < 64; ++s) {
                u32 lo = (u32)__builtin_amdgcn_readlane((int)vlo, s);
                u32 hi = (u32)__builtin_amdgcn_readlane((int)vhi, s);
                u64 vj = ((u64)hi << 32) | lo;
                r += (vj > e) ? 1u : 0u;
            }
        }
        if (val && r < target) {
            u32 k = (u32)(e >> 32);
            u32 loc = ~(u32)e;
            size_t src = (size_t)b * NTOT + loc;
            size_t o = (size_t)b * TOPN + r;
            tscore[o] = __uint_as_float(k & 0x7FFFFFFFu);
            tcls[o] = (float)clsidx[src];
            tbox[o] = boxes[src];
        }
    }
}

// -------------------------------------------------------------------------
// Stage 3: suppression-bit matrix.  4 rows per 256-thread block.
// -------------------------------------------------------------------------
__global__ __launch_bounds__(256) void iou_kernel(
    const float4* __restrict__ tbox, u64* __restrict__ sup)
{
    __shared__ float4 sbox[TOPN];
    int b = blockIdx.y;
    int tid = threadIdx.x, lane = tid & 63, wave = tid >> 6;
    const float4* tb = tbox + (size_t)b * TOPN;
    for (int i = tid; i < TOPN; i += 256) sbox[i] = tb[i];
    __syncthreads();
    int i = blockIdx.x * 4 + wave;
    float4 bi = sbox[i];
    float areai = fmaxf((bi.z - bi.x) * (bi.w - bi.y), 0.0001f);
    u64* row = sup + ((size_t)b * TOPN + i) * 16;
#pragma unroll
    for (int w = 0; w < 16; ++w) {
        int col = w * 64 + lane;
        bool bit = false;
        if (col < TOPN) {
            float4 bj = sbox[col];
            float areaj = fmaxf((bj.z - bj.x) * (bj.w - bj.y), 0.0001f);
            float tlx = fmaxf(bi.x, bj.x), tly = fmaxf(bi.y, bj.y);
            float brx = fminf(bi.z, bj.z), bry = fminf(bi.w, bj.w);
            float ow = fmaxf(brx - tlx, 0.f), oh = fmaxf(bry - tly, 0.f);
            float inter = ow * oh;
            float uni = fmaxf(areai + areaj - inter, 0.0001f);
            bit = (col > i) && (inter / uni >= 0.6f);
        }
        u64 m = __ballot(bit);
        if (lane == 0) row[w] = m;
    }
}

// -------------------------------------------------------------------------
// Stage 4: greedy serial scan + popcount-rank output (no Hillis-Steele).
// -------------------------------------------------------------------------
#define CHROWS 128
#define NCHUNK 8

__global__ __launch_bounds__(1024) void finalize_kernel(
    const float* __restrict__ tscore, const float* __restrict__ tcls,
    const float4* __restrict__ tbox, const u64* __restrict__ sup,
    float* __restrict__ out)
{
    __shared__ u64 mat[2][CHROWS * 16];
    __shared__ u32 validsh[TOPN];
    __shared__ u64 removed_sh[16];
    __shared__ u32 wpref[17];
    int b = blockIdx.x, tid = threadIdx.x;
    int wave = tid >> 6, lane = tid & 63;

    for (int i = tid; i < TOPN; i += 1024)
        validsh[i] = (tscore[(size_t)b * TOPN + i] > 0.05f) ? 1u : 0u;

    const u64* supb = sup + (size_t)b * TOPN * 16;
    for (int idx = tid; idx < CHROWS * 16; idx += 1024)
        mat[0][idx] = supb[idx];
    __syncthreads();

    u64 my = 0;
    if (wave == 0) {
#pragma unroll
        for (int w2 = 0; w2 < 16; ++w2) {
            int i = w2 * 64 + lane;
            bool v = (i < TOPN) ? (validsh[i] != 0) : false;
            u64 m = __ballot(v);
            if (lane == w2) my = ~m;
        }
    }

    for (int chunk = 0; chunk < NCHUNK; ++chunk) {
        if (wave > 0 && chunk + 1 < NCHUNK) {
            int nr = (chunk + 1 == NCHUNK - 1) ? (TOPN - (NCHUNK - 1) * CHROWS) : CHROWS;
            const u64* src = supb + (size_t)(chunk + 1) * CHROWS * 16;
            u64* dst = mat[(chunk + 1) & 1];
            for (int idx = tid - 64; idx < nr * 16; idx += 960)
                dst[idx] = src[idx];
        }
        if (wave == 0) {
            int r0 = chunk * CHROWS;
            int rows = (chunk == NCHUNK - 1) ? (TOPN - r0) : CHROWS;
            int lw = lane & 15;
            const u64* M = mat[chunk & 1];
            for (int sub = 0; sub < rows; sub += 64) {
                int w2 = (r0 + sub) >> 6;
                u64 cur = __shfl(my, w2);
                int nsub = rows - sub; if (nsub > 64) nsub = 64;
                const u64* R = M + sub * 16;
                int ngrp = nsub >> 3;
                u64 cme[8], cww[8];
#pragma unroll
                for (int g = 0; g < 8; ++g) { cme[g] = R[g*16 + lw]; cww[g] = R[g*16 + w2]; }
                for (int grp = 0; grp < ngrp; ++grp) {
                    u64 nme[8] = {0,0,0,0,0,0,0,0}, nww[8] = {0,0,0,0,0,0,0,0};
                    if (grp + 1 < ngrp) {
                        const u64* Rn = R + (grp + 1) * 128;
#pragma unroll
                        for (int g = 0; g < 8; ++g) { nme[g] = Rn[g*16 + lw]; nww[g] = Rn[g*16 + w2]; }
                    }
#pragma unroll
                    for (int g = 0; g < 8; ++g) {
                        int u = grp * 8 + g;
                        u64 bit = (cur >> u) & 1ull;
                        u64 act = bit - 1ull;
                        cur |= cww[g] & act;
                        my  |= cme[g] & act;
                    }
#pragma unroll
                    for (int g = 0; g < 8; ++g) { cme[g] = nme[g]; cww[g] = nww[g]; }
                }
            }
        }
        __syncthreads();
    }
    if (wave == 0) {
        if (lane < 16) removed_sh[lane] = my;
        u32 pc = (lane < 16) ? (u32)__popcll(~my) : 0u;
#pragma unroll
        for (int off = 1; off < 16; off <<= 1) {
            u32 y = __shfl_up(pc, off);
            if (lane >= off) pc += y;
        }
        if (lane < 16) wpref[lane + 1] = pc;
        if (lane == 0) wpref[0] = 0;
    }
    __syncthreads();

    float* out_s = out;
    float* out_c = out + NBATCH * MAXOBJ;
    float* out_b = out + 2 * NBATCH * MAXOBJ;
    if (tid < MAXOBJ)     { out_s[b * MAXOBJ + tid] = -1.f; out_c[b * MAXOBJ + tid] = -1.f; }
    if (tid < MAXOBJ * 4) out_b[b * MAXOBJ * 4 + tid] = 0.f;
    __syncthreads();
    if (tid < TOPN) {
        u64 kw = ~removed_sh[tid >> 6];       // keep-word (invalid already removed)
        if ((kw >> (tid & 63)) & 1ull) {
            int rank = (int)wpref[tid >> 6] + (int)__popcll(kw & ((1ull << (tid & 63)) - 1ull));
            if (rank < MAXOBJ) {
                size_t o = (size_t)b * TOPN + tid;
                out_s[b * MAXOBJ + rank] = tscore[o];
                out_c[b * MAXOBJ + rank] = tcls[o];
                ((float4*)out_b)[b * MAXOBJ + rank] = tbox[o];
            }
        }
    }
}

// -------------------------------------------------------------------------
// Workspace layout (bytes), total 10,812,416:
//   keys    u32 [16][21824]     @ 0
//   clsidx  i32 [16][21824]     @ 1,396,736
//   boxes   f4  [16][21824]     @ 2,793,472
//   tscore  f32 [16][1000]      @ 8,380,416
//   tcls    f32 [16][1000]      @ 8,444,416
//   tbox    f4  [16][1000]      @ 8,508,416
//   sup     u64 [16][1000][16]  @ 8,764,416  (iou output; clobbers the below)
//   candbuf u64 [16][8192]      @ 8,764,416  (dead after rank)
//   hist0   u32 [16][2048]      @ 9,812,992  (dead after pivot)
//   gcnt    u32 [16]            @ 9,944,064
//   params  u32 [16][2]         @ 9,944,128
// -------------------------------------------------------------------------
extern "C" void kernel_launch(void* const* d_in, const int* in_sizes, int n_in,
                              void* d_out, int out_size, void* d_ws, size_t ws_size,
                              hipStream_t stream) {
    (void)in_sizes; (void)n_in; (void)out_size; (void)ws_size;
    const float* cls[5]; const float* reg[5]; const float* ctr[5];
    for (int l = 0; l < 5; ++l) {
        cls[l] = (const float*)d_in[4 * l + 0];
        reg[l] = (const float*)d_in[4 * l + 1];
        ctr[l] = (const float*)d_in[4 * l + 2];
    }
    char* w = (char*)d_ws;
    u32*    keys   = (u32*)(w + 0);
    int*    clsidx = (int*)(w + 1396736);
    float4* boxes  = (float4*)(w + 2793472);
    float*  tscore = (float*)(w + 8380416);
    float*  tcls   = (float*)(w + 8444416);
    float4* tbox   = (float4*)(w + 8508416);
    u64*    sup    = (u64*)(w + 8764416);
    u64*    candbuf= (u64*)(w + 8764416);
    u32*    hist0  = (u32*)(w + 9812992);
    u32*    gcnt   = (u32*)(w + 9944064);
    u32*    params = (u32*)(w + 9944128);

    zero_kernel<<<33, 1024, 0, stream>>>(hist0);   // hist0 + gcnt contiguous
    decode_kernel<<<dim3((NTOT + 255) / 256, NBATCH), 256, 0, stream>>>(
        cls[0], cls[1], cls[2], cls[3], cls[4],
        reg[0], reg[1], reg[2], reg[3], reg[4],
        ctr[0], ctr[1], ctr[2], ctr[3], ctr[4],
        keys, clsidx, boxes, hist0);
    pivot_kernel<<<NBATCH, 1024, 0, stream>>>(keys, hist0, params, tscore, tcls, tbox);
    gather_kernel<<<dim3((NTOT + 255) / 256, NBATCH), 256, 0, stream>>>(keys, params, candbuf, gcnt);
    rank_kernel<<<dim3(8, NBATCH), 256, 0, stream>>>(candbuf, gcnt, params, clsidx, boxes,
                                                     tscore, tcls, tbox);
    iou_kernel<<<dim3(TOPN / 4, NBATCH), 256, 0, stream>>>(tbox, sup);
    finalize_kernel<<<NBATCH, 1024, 0, stream>>>(tscore, tcls, tbox, sup, (float*)d_out);
}

// Round 5
// 287.498 us; speedup vs baseline: 1.1949x; 1.1949x over previous
//
#include <hip/hip_runtime.h>
#include <stdint.h>

typedef unsigned int u32;
typedef unsigned long long u64;

#define NTOT 21824   // 128*128 + 64*64 + 32*32 + 16*16 + 8*8
#define NBATCH 16
#define TOPN 1000
#define MAXOBJ 100
#define CAP 2048     // refine until candidate count <= CAP
#define CAPC 8192    // global candidate buffer capacity per batch

// -------------------------------------------------------------------------
// Stage 0: zero hist0 (16*2048 u32) + padded gcnt (16*32 u32), contiguous.
// -------------------------------------------------------------------------
__global__ void zero_kernel(u32* __restrict__ h) {
    int i = blockIdx.x * 1024 + threadIdx.x;
    if (i < NBATCH * 2048 + NBATCH * 32) h[i] = 0;
}

// -------------------------------------------------------------------------
// Stage 1: decode + fused per-batch 11-bit key histogram.
// -------------------------------------------------------------------------
__global__ __launch_bounds__(256) void decode_kernel(
    const float* __restrict__ cls0, const float* __restrict__ cls1,
    const float* __restrict__ cls2, const float* __restrict__ cls3,
    const float* __restrict__ cls4,
    const float* __restrict__ reg0, const float* __restrict__ reg1,
    const float* __restrict__ reg2, const float* __restrict__ reg3,
    const float* __restrict__ reg4,
    const float* __restrict__ ctr0, const float* __restrict__ ctr1,
    const float* __restrict__ ctr2, const float* __restrict__ ctr3,
    const float* __restrict__ ctr4,
    u32* __restrict__ keys, int* __restrict__ clsidx, float4* __restrict__ boxes,
    u32* __restrict__ hist0)
{
    __shared__ u32 bh[2048];
    for (int i = threadIdx.x; i < 2048; i += 256) bh[i] = 0;
    __syncthreads();

    int loc = blockIdx.x * 256 + threadIdx.x;
    int b = blockIdx.y;
    if (loc < NTOT) {
        const float *cp, *rp, *tp;
        int li, wsh; float st;
        if (loc < 16384)      { li = loc;         wsh = 7; st = 8.f;   size_t o = (size_t)b*16384 + li; cp = cls0 + o*80; rp = reg0 + o*4; tp = ctr0 + o; }
        else if (loc < 20480) { li = loc - 16384; wsh = 6; st = 16.f;  size_t o = (size_t)b*4096  + li; cp = cls1 + o*80; rp = reg1 + o*4; tp = ctr1 + o; }
        else if (loc < 21504) { li = loc - 20480; wsh = 5; st = 32.f;  size_t o = (size_t)b*1024  + li; cp = cls2 + o*80; rp = reg2 + o*4; tp = ctr2 + o; }
        else if (loc < 21760) { li = loc - 21504; wsh = 4; st = 64.f;  size_t o = (size_t)b*256   + li; cp = cls3 + o*80; rp = reg3 + o*4; tp = ctr3 + o; }
        else                  { li = loc - 21760; wsh = 3; st = 128.f; size_t o = (size_t)b*64    + li; cp = cls4 + o*80; rp = reg4 + o*4; tp = ctr4 + o; }
        int wx = li & ((1 << wsh) - 1);
        int hy = li >> wsh;
        float px = ((float)wx + 0.5f) * st;
        float py = ((float)hy + 0.5f) * st;

        const float4* c4 = (const float4*)cp;
        float maxv = -1.0f; int arg = 0;
#pragma unroll
        for (int q = 0; q < 20; ++q) {
            float4 v = c4[q];
            if (v.x > maxv) { maxv = v.x; arg = 4*q;     }
            if (v.y > maxv) { maxv = v.y; arg = 4*q + 1; }
            if (v.z > maxv) { maxv = v.z; arg = 4*q + 2; }
            if (v.w > maxv) { maxv = v.w; arg = 4*q + 3; }
        }
        float ctr = *tp;
        float score = sqrtf(maxv * ctr);       // correctly-rounded fp32 sqrt
        float4 r = *(const float4*)rp;
        float4 bx;
        bx.x = truncf(px - r.x); bx.y = truncf(py - r.y);
        bx.z = truncf(px + r.z); bx.w = truncf(py + r.w);
        size_t o = (size_t)b * NTOT + loc;
        u32 key = (score > 0.05f) ? (__float_as_uint(score) | 0x80000000u) : 0u;
        keys[o] = key;
        clsidx[o] = arg;
        boxes[o] = bx;
        if (key) atomicAdd(&bh[key >> 21], 1u);
    }
    __syncthreads();
    for (int i = threadIdx.x; i < 2048; i += 256) {
        u32 c = bh[i];
        if (c) atomicAdd(&hist0[b * 2048 + i], c);
    }
}

// -------------------------------------------------------------------------
// Stage 2a: exact pivot P per batch via radix refinement (1 block/batch).
// Also writes output defaults.  params[b] = {P, target}.
// -------------------------------------------------------------------------
__global__ __launch_bounds__(1024) void pivot_kernel(
    const u32* __restrict__ keys, const u32* __restrict__ hist0,
    u32* __restrict__ params,
    float* __restrict__ tscore, float* __restrict__ tcls, float4* __restrict__ tbox)
{
    __shared__ u32 shist[2048];
    __shared__ u32 s_wtot[16];
    __shared__ int s_tf;
    __shared__ u32 s_C, s_above;
    int b = blockIdx.x, tid = threadIdx.x;
    int lane = tid & 63, wave = tid >> 6;
    const u32* kb = keys + (size_t)b * NTOT;

    // defaults for outputs
    for (int i = tid; i < TOPN; i += 1024) {
        size_t o = (size_t)b * TOPN + i;
        tscore[o] = -1.0f; tcls[o] = -1.0f;
        tbox[o] = make_float4(0.f, 0.f, 0.f, 0.f);
    }

    // ---- level 1: suffix scan of hist0 ----
    u32 h0 = hist0[b * 2048 + 2 * tid];
    u32 h1 = hist0[b * 2048 + 2 * tid + 1];
    if (tid == 0) s_tf = -1;
    u32 x = h0 + h1;
#pragma unroll
    for (int off = 1; off < 64; off <<= 1) {
        u32 y = __shfl_down(x, off);
        if (lane + off < 64) x += y;
    }
    if (lane == 0) s_wtot[wave] = x;
    __syncthreads();
    u32 wsuf = 0, tot = 0;
    for (int w2 = 0; w2 < 16; ++w2) { u32 v = s_wtot[w2]; tot += v; if (w2 > wave) wsuf += v; }
    u32 suf0 = x + wsuf, suf1 = suf0 - h0;
    u32 target = (tot < TOPN) ? tot : TOPN;

    if (target > 0) {
        if (suf0 >= target) atomicMax(&s_tf, 2 * tid);
        if (suf1 >= target) atomicMax(&s_tf, 2 * tid + 1);
    }
    __syncthreads();
    int t0 = s_tf;
    if (target > 0) {
        if (2 * tid == t0)     { s_C = suf0; s_above = suf0 - h0; }
        if (2 * tid + 1 == t0) { s_C = suf1; s_above = suf1 - h1; }
    }
    __syncthreads();
    u32 C0 = (target > 0) ? s_C : 0;
    u32 above0 = (target > 0) ? s_above : 0;

    // ---- level 2 (scan keys in bin t0) ----
    bool need2 = (target > 0 && C0 > CAP);
    int t1 = 0; u32 C1 = 0, above1 = 0;
    shist[2 * tid] = 0; shist[2 * tid + 1] = 0;
    if (tid == 0) s_tf = -1;
    __syncthreads();
    if (need2) {
        for (int i = tid; i < NTOT; i += 1024) {
            u32 k = kb[i];
            if (k && (int)(k >> 21) == t0) atomicAdd(&shist[(k >> 10) & 2047], 1u);
        }
    }
    __syncthreads();
    {
        u32 g0 = shist[2 * tid], g1 = shist[2 * tid + 1];
        u32 x2 = g0 + g1;
#pragma unroll
        for (int off = 1; off < 64; off <<= 1) {
            u32 y = __shfl_down(x2, off);
            if (lane + off < 64) x2 += y;
        }
        if (lane == 0) s_wtot[wave] = x2;
        __syncthreads();
        u32 ws2 = 0;
        for (int w2 = wave + 1; w2 < 16; ++w2) ws2 += s_wtot[w2];
        u32 sa0 = x2 + ws2, sa1 = sa0 - g0;
        u32 need2c = target - above0;
        if (need2) {
            if (sa0 >= need2c) atomicMax(&s_tf, 2 * tid);
            if (sa1 >= need2c) atomicMax(&s_tf, 2 * tid + 1);
        }
        __syncthreads();
        t1 = s_tf;
        if (need2) {
            if (2 * tid == t1)     { s_C = above0 + sa0; s_above = above0 + sa0 - g0; }
            if (2 * tid + 1 == t1) { s_C = above0 + sa1; s_above = above0 + sa1 - g1; }
        }
        __syncthreads();
        if (need2) { C1 = s_C; above1 = s_above; }
    }

    // ---- level 3 (scan keys in bin (t0,t1)) ----
    bool need3 = (need2 && C1 > CAP);
    int t2 = 0;
    __syncthreads();
    shist[2 * tid] = 0; shist[2 * tid + 1] = 0;
    if (tid == 0) s_tf = -1;
    __syncthreads();
    if (need3) {
        for (int i = tid; i < NTOT; i += 1024) {
            u32 k = kb[i];
            if (k && (int)(k >> 21) == t0 && (int)((k >> 10) & 2047) == t1)
                atomicAdd(&shist[k & 1023], 1u);
        }
    }
    __syncthreads();
    {
        u32 g = shist[tid];
        u32 x3 = g;
#pragma unroll
        for (int off = 1; off < 64; off <<= 1) {
            u32 y = __shfl_down(x3, off);
            if (lane + off < 64) x3 += y;
        }
        if (lane == 0) s_wtot[wave] = x3;
        __syncthreads();
        u32 ws3 = 0;
        for (int w2 = wave + 1; w2 < 16; ++w2) ws3 += s_wtot[w2];
        u32 sb = x3 + ws3;
        if (need3) {
            u32 need3c = target - above1;
            if (sb >= need3c && tid < 1024) atomicMax(&s_tf, tid);
        }
        __syncthreads();
        t2 = s_tf;
    }

    if (tid == 0) {
        u32 P;
        if (target == 0)      P = 0xFFFFFFFFu;
        else if (!need2)      P = (u32)t0 << 21;
        else if (!need3)      P = ((u32)t0 << 21) | ((u32)t1 << 10);
        else                  P = ((u32)t0 << 21) | ((u32)t1 << 10) | (u32)t2;
        params[2 * b] = P;
        params[2 * b + 1] = target;
    }
}

// -------------------------------------------------------------------------
// Stage 2b: gather all keys >= P into candbuf.  ONE global atomic per
// block (not per wave), and per-batch counters padded 128 B apart so the
// 16 counters live on 16 distinct cache lines (R4's 61 us was 5504 atomics
// on a single line).
// -------------------------------------------------------------------------
__global__ __launch_bounds__(256) void gather_kernel(
    const u32* __restrict__ keys, const u32* __restrict__ params,
    u64* __restrict__ candbuf, u32* __restrict__ gcnt)
{
    __shared__ u32 s_wcnt[4];
    __shared__ u32 s_base;
    int b = blockIdx.y;
    int tid = threadIdx.x;
    int lane = tid & 63, wave = tid >> 6;
    u32 P = params[2 * b];
    int i = blockIdx.x * 256 + tid;
    u32 k = (i < NTOT) ? keys[(size_t)b * NTOT + i] : 0u;
    bool pass = (k != 0u) && (k >= P);
    u64 mask = __ballot(pass);
    if (lane == 0) s_wcnt[wave] = (u32)__popcll(mask);
    __syncthreads();
    if (tid == 0) {
        u32 tot = s_wcnt[0] + s_wcnt[1] + s_wcnt[2] + s_wcnt[3];
        s_base = tot ? atomicAdd(&gcnt[b * 32], tot) : 0u;
    }
    __syncthreads();
    if (pass) {
        u32 woff = 0;
        for (int w2 = 0; w2 < wave; ++w2) woff += s_wcnt[w2];
        u32 pos = s_base + woff + (u32)__popcll(mask & ((1ull << lane) - 1ull));
        if (pos < CAPC)
            candbuf[(size_t)b * CAPC + pos] = ((u64)k << 32) | (u32)(~i);
    }
}

// -------------------------------------------------------------------------
// Stage 2c: rank-by-count + scatter (v_readlane broadcast compares).
// -------------------------------------------------------------------------
__global__ __launch_bounds__(256) void rank_kernel(
    const u64* __restrict__ candbuf, const u32* __restrict__ gcnt,
    const u32* __restrict__ params,
    const int* __restrict__ clsidx, const float4* __restrict__ boxes,
    float* __restrict__ tscore, float* __restrict__ tcls, float4* __restrict__ tbox)
{
    int b = blockIdx.y;
    int lane = threadIdx.x & 63;
    u32 M = gcnt[b * 32]; if (M > CAPC) M = CAPC;
    u32 target = params[2 * b + 1];
    const u64* cb = candbuf + (size_t)b * CAPC;
    u32 Mr = (M + 63u) & ~63u;

    u32 wbase0 = blockIdx.x * 256 + (threadIdx.x & ~63u);
    for (u32 base = wbase0; base < M; base += 8 * 256) {   // uniform per wave
        u32 i0 = base + lane;
        bool val = (i0 < M);
        u64 e = val ? cb[i0] : ~0ull;
        u32 r = 0;
        for (u32 c0 = 0; c0 < Mr; c0 += 64) {
            u32 j = c0 + lane;
            u64 v = (j < M) ? cb[j] : 0ull;   // 0 is never > any candidate
            u32 vlo = (u32)v, vhi = (u32)(v >> 32);
#pragma unroll
            for (int s = 0; s < 64; ++s) {
                u32 lo = (u32)__builtin_amdgcn_readlane((int)vlo, s);
                u32 hi = (u32)__builtin_amdgcn_readlane((int)vhi, s);
                u64 vj = ((u64)hi << 32) | lo;
                r += (vj > e) ? 1u : 0u;
            }
        }
        if (val && r < target) {
            u32 k = (u32)(e >> 32);
            u32 loc = ~(u32)e;
            size_t src = (size_t)b * NTOT + loc;
            size_t o = (size_t)b * TOPN + r;
            tscore[o] = __uint_as_float(k & 0x7FFFFFFFu);
            tcls[o] = (float)clsidx[src];
            tbox[o] = boxes[src];
        }
    }
}

// -------------------------------------------------------------------------
// Stage 3: suppression-bit matrix.  4 rows per 256-thread block.
// -------------------------------------------------------------------------
__global__ __launch_bounds__(256) void iou_kernel(
    const float4* __restrict__ tbox, u64* __restrict__ sup)
{
    __shared__ float4 sbox[TOPN];
    int b = blockIdx.y;
    int tid = threadIdx.x, lane = tid & 63, wave = tid >> 6;
    const float4* tb = tbox + (size_t)b * TOPN;
    for (int i = tid; i < TOPN; i += 256) sbox[i] = tb[i];
    __syncthreads();
    int i = blockIdx.x * 4 + wave;
    float4 bi = sbox[i];
    float areai = fmaxf((bi.z - bi.x) * (bi.w - bi.y), 0.0001f);
    u64* row = sup + ((size_t)b * TOPN + i) * 16;
#pragma unroll
    for (int w = 0; w < 16; ++w) {
        int col = w * 64 + lane;
        bool bit = false;
        if (col < TOPN) {
            float4 bj = sbox[col];
            float areaj = fmaxf((bj.z - bj.x) * (bj.w - bj.y), 0.0001f);
            float tlx = fmaxf(bi.x, bj.x), tly = fmaxf(bi.y, bj.y);
            float brx = fminf(bi.z, bj.z), bry = fminf(bi.w, bj.w);
            float ow = fmaxf(brx - tlx, 0.f), oh = fmaxf(bry - tly, 0.f);
            float inter = ow * oh;
            float uni = fmaxf(areai + areaj - inter, 0.0001f);
            bit = (col > i) && (inter / uni >= 0.6f);
        }
        u64 m = __ballot(bit);
        if (lane == 0) row[w] = m;
    }
}

// -------------------------------------------------------------------------
// Stage 4: greedy serial scan + popcount-rank output.
// -------------------------------------------------------------------------
#define CHROWS 128
#define NCHUNK 8

__global__ __launch_bounds__(1024) void finalize_kernel(
    const float* __restrict__ tscore, const float* __restrict__ tcls,
    const float4* __restrict__ tbox, const u64* __restrict__ sup,
    float* __restrict__ out)
{
    __shared__ u64 mat[2][CHROWS * 16];
    __shared__ u32 validsh[TOPN];
    __shared__ u64 removed_sh[16];
    __shared__ u32 wpref[17];
    int b = blockIdx.x, tid = threadIdx.x;
    int wave = tid >> 6, lane = tid & 63;

    for (int i = tid; i < TOPN; i += 1024)
        validsh[i] = (tscore[(size_t)b * TOPN + i] > 0.05f) ? 1u : 0u;

    const u64* supb = sup + (size_t)b * TOPN * 16;
    for (int idx = tid; idx < CHROWS * 16; idx += 1024)
        mat[0][idx] = supb[idx];
    __syncthreads();

    u64 my = 0;
    if (wave == 0) {
#pragma unroll
        for (int w2 = 0; w2 < 16; ++w2) {
            int i = w2 * 64 + lane;
            bool v = (i < TOPN) ? (validsh[i] != 0) : false;
            u64 m = __ballot(v);
            if (lane == w2) my = ~m;
        }
    }

    for (int chunk = 0; chunk < NCHUNK; ++chunk) {
        if (wave > 0 && chunk + 1 < NCHUNK) {
            int nr = (chunk + 1 == NCHUNK - 1) ? (TOPN - (NCHUNK - 1) * CHROWS) : CHROWS;
            const u64* src = supb + (size_t)(chunk + 1) * CHROWS * 16;
            u64* dst = mat[(chunk + 1) & 1];
            for (int idx = tid - 64; idx < nr * 16; idx += 960)
                dst[idx] = src[idx];
        }
        if (wave == 0) {
            int r0 = chunk * CHROWS;
            int rows = (chunk == NCHUNK - 1) ? (TOPN - r0) : CHROWS;
            int lw = lane & 15;
            const u64* M = mat[chunk & 1];
            for (int sub = 0; sub < rows; sub += 64) {
                int w2 = (r0 + sub) >> 6;
                u64 cur = __shfl(my, w2);
                int nsub = rows - sub; if (nsub > 64) nsub = 64;
                const u64* R = M + sub * 16;
                int ngrp = nsub >> 3;
                u64 cme[8], cww[8];
#pragma unroll
                for (int g = 0; g < 8; ++g) { cme[g] = R[g*16 + lw]; cww[g] = R[g*16 + w2]; }
                for (int grp = 0; grp < ngrp; ++grp) {
                    u64 nme[8] = {0,0,0,0,0,0,0,0}, nww[8] = {0,0,0,0,0,0,0,0};
                    if (grp + 1 < ngrp) {
                        const u64* Rn = R + (grp + 1) * 128;
#pragma unroll
                        for (int g = 0; g < 8; ++g) { nme[g] = Rn[g*16 + lw]; nww[g] = Rn[g*16 + w2]; }
                    }
#pragma unroll
                    for (int g = 0; g < 8; ++g) {
                        int u = grp * 8 + g;
                        u64 bit = (cur >> u) & 1ull;
                        u64 act = bit - 1ull;
                        cur |= cww[g] & act;
                        my  |= cme[g] & act;
                    }
#pragma unroll
                    for (int g = 0; g < 8; ++g) { cme[g] = nme[g]; cww[g] = nww[g]; }
                }
            }
        }
        __syncthreads();
    }
    if (wave == 0) {
        if (lane < 16) removed_sh[lane] = my;
        u32 pc = (lane < 16) ? (u32)__popcll(~my) : 0u;
#pragma unroll
        for (int off = 1; off < 16; off <<= 1) {
            u32 y = __shfl_up(pc, off);
            if (lane >= off) pc += y;
        }
        if (lane < 16) wpref[lane + 1] = pc;
        if (lane == 0) wpref[0] = 0;
    }
    __syncthreads();

    float* out_s = out;
    float* out_c = out + NBATCH * MAXOBJ;
    float* out_b = out + 2 * NBATCH * MAXOBJ;
    if (tid < MAXOBJ)     { out_s[b * MAXOBJ + tid] = -1.f; out_c[b * MAXOBJ + tid] = -1.f; }
    if (tid < MAXOBJ * 4) out_b[b * MAXOBJ * 4 + tid] = 0.f;
    __syncthreads();
    if (tid < TOPN) {
        u64 kw = ~removed_sh[tid >> 6];       // keep-word (invalid already removed)
        if ((kw >> (tid & 63)) & 1ull) {
            int rank = (int)wpref[tid >> 6] + (int)__popcll(kw & ((1ull << (tid & 63)) - 1ull));
            if (rank < MAXOBJ) {
                size_t o = (size_t)b * TOPN + tid;
                out_s[b * MAXOBJ + rank] = tscore[o];
                out_c[b * MAXOBJ + rank] = tcls[o];
                ((float4*)out_b)[b * MAXOBJ + rank] = tbox[o];
            }
        }
    }
}

// -------------------------------------------------------------------------
// Workspace layout (bytes), total 10,812,416:
//   keys    u32 [16][21824]     @ 0
//   clsidx  i32 [16][21824]     @ 1,396,736
//   boxes   f4  [16][21824]     @ 2,793,472
//   tscore  f32 [16][1000]      @ 8,380,416
//   tcls    f32 [16][1000]      @ 8,444,416
//   tbox    f4  [16][1000]      @ 8,508,416
//   sup     u64 [16][1000][16]  @ 8,764,416  (iou output; clobbers the below)
//   candbuf u64 [16][8192]      @ 8,764,416  (dead after rank)
//   hist0   u32 [16][2048]      @ 9,812,992  (dead after pivot)
//   gcnt    u32 [16][32] padded @ 9,944,064  (128 B per batch counter)
//   params  u32 [16][2]         @ 9,946,112
// -------------------------------------------------------------------------
extern "C" void kernel_launch(void* const* d_in, const int* in_sizes, int n_in,
                              void* d_out, int out_size, void* d_ws, size_t ws_size,
                              hipStream_t stream) {
    (void)in_sizes; (void)n_in; (void)out_size; (void)ws_size;
    const float* cls[5]; const float* reg[5]; const float* ctr[5];
    for (int l = 0; l < 5; ++l) {
        cls[l] = (const float*)d_in[4 * l + 0];
        reg[l] = (const float*)d_in[4 * l + 1];
        ctr[l] = (const float*)d_in[4 * l + 2];
    }
    char* w = (char*)d_ws;
    u32*    keys   = (u32*)(w + 0);
    int*    clsidx = (int*)(w + 1396736);
    float4* boxes  = (float4*)(w + 2793472);
    float*  tscore = (float*)(w + 8380416);
    float*  tcls   = (float*)(w + 8444416);
    float4* tbox   = (float4*)(w + 8508416);
    u64*    sup    = (u64*)(w + 8764416);
    u64*    candbuf= (u64*)(w + 8764416);
    u32*    hist0  = (u32*)(w + 9812992);
    u32*    gcnt   = (u32*)(w + 9944064);
    u32*    params = (u32*)(w + 9946112);

    zero_kernel<<<33, 1024, 0, stream>>>(hist0);   // hist0 + padded gcnt contiguous
    decode_kernel<<<dim3((NTOT + 255) / 256, NBATCH), 256, 0, stream>>>(
        cls[0], cls[1], cls[2], cls[3], cls[4],
        reg[0], reg[1], reg[2], reg[3], reg[4],
        ctr[0], ctr[1], ctr[2], ctr[3], ctr[4],
        keys, clsidx, boxes, hist0);
    pivot_kernel<<<NBATCH, 1024, 0, stream>>>(keys, hist0, params, tscore, tcls, tbox);
    gather_kernel<<<dim3((NTOT + 255) / 256, NBATCH), 256, 0, stream>>>(keys, params, candbuf, gcnt);
    rank_kernel<<<dim3(8, NBATCH), 256, 0, stream>>>(candbuf, gcnt, params, clsidx, boxes,
                                                     tscore, tcls, tbox);
    iou_kernel<<<dim3(TOPN / 4, NBATCH), 256, 0, stream>>>(tbox, sup);
    finalize_kernel<<<NBATCH, 1024, 0, stream>>>(tscore, tcls, tbox, sup, (float*)d_out);
}

// Round 6
// 277.983 us; speedup vs baseline: 1.2358x; 1.0342x over previous
//
#include <hip/hip_runtime.h>
#include <stdint.h>

typedef unsigned int u32;
typedef unsigned long long u64;

#define NTOT 21824   // 128*128 + 64*64 + 32*32 + 16*16 + 8*8
#define NBATCH 16
#define TOPN 1000
#define MAXOBJ 100
#define CAP 2048     // refine until candidate count <= CAP
#define CAPC 8192    // global candidate buffer capacity per batch

// -------------------------------------------------------------------------
// Stage 0: zero hist0 (16*2048 u32) + padded gcnt (16*32 u32), contiguous.
// -------------------------------------------------------------------------
__global__ void zero_kernel(u32* __restrict__ h) {
    int i = blockIdx.x * 1024 + threadIdx.x;
    if (i < NBATCH * 2048 + NBATCH * 32) h[i] = 0;
}

// -------------------------------------------------------------------------
// Stage 1: decode (argmax over 80 classes + score key) + fused histogram.
// Quad-per-location: 4 lanes share one location; lane j reads float4s
// j, j+4, ..., j+16 -> each quad's load is a contiguous 64 B segment
// (wave touches 16 lines/instr instead of 64; block WS 20 KB < L1).
// reg is NOT read and boxes are NOT written here (deferred to rank).
// -------------------------------------------------------------------------
__global__ __launch_bounds__(256) void decode_kernel(
    const float* __restrict__ cls0, const float* __restrict__ cls1,
    const float* __restrict__ cls2, const float* __restrict__ cls3,
    const float* __restrict__ cls4,
    const float* __restrict__ ctr0, const float* __restrict__ ctr1,
    const float* __restrict__ ctr2, const float* __restrict__ ctr3,
    const float* __restrict__ ctr4,
    u32* __restrict__ keys, int* __restrict__ clsidx,
    u32* __restrict__ hist0)
{
    __shared__ u32 bh[2048];
    for (int i = threadIdx.x; i < 2048; i += 256) bh[i] = 0;
    __syncthreads();

    int tid = threadIdx.x;
    int g = tid >> 2, j = tid & 3;          // location-in-block, quad sub
    int loc = blockIdx.x * 64 + g;          // level-uniform per block
    int b = blockIdx.y;
    if (loc < NTOT) {
        const float *cp, *tp;
        if (loc < 16384)      { size_t o = (size_t)b*16384 + loc;          cp = cls0 + o*80; tp = ctr0 + o; }
        else if (loc < 20480) { size_t o = (size_t)b*4096  + (loc-16384);  cp = cls1 + o*80; tp = ctr1 + o; }
        else if (loc < 21504) { size_t o = (size_t)b*1024  + (loc-20480);  cp = cls2 + o*80; tp = ctr2 + o; }
        else if (loc < 21760) { size_t o = (size_t)b*256   + (loc-21504);  cp = cls3 + o*80; tp = ctr3 + o; }
        else                  { size_t o = (size_t)b*64    + (loc-21760);  cp = cls4 + o*80; tp = ctr4 + o; }

        const float4* c4 = (const float4*)cp;
        float maxv = -1.0f; int arg = 0;
#pragma unroll
        for (int q = 0; q < 5; ++q) {
            float4 v = c4[j + 4*q];
            int ch = 16*q + 4*j;
            if (v.x > maxv) { maxv = v.x; arg = ch;     }
            if (v.y > maxv) { maxv = v.y; arg = ch + 1; }
            if (v.z > maxv) { maxv = v.z; arg = ch + 2; }
            if (v.w > maxv) { maxv = v.w; arg = ch + 3; }
        }
        // quad reduction, exact first-max tie-break (lowest channel wins)
#pragma unroll
        for (int d = 1; d <= 2; d <<= 1) {
            float ov = __shfl_xor(maxv, d);
            int   oa = __shfl_xor(arg, d);
            if (ov > maxv || (ov == maxv && oa < arg)) { maxv = ov; arg = oa; }
        }
        if (j == 0) {
            float score = sqrtf(maxv * (*tp));   // correctly-rounded fp32 sqrt
            u32 key = (score > 0.05f) ? (__float_as_uint(score) | 0x80000000u) : 0u;
            size_t o = (size_t)b * NTOT + loc;
            keys[o] = key;
            clsidx[o] = arg;
            if (key) atomicAdd(&bh[key >> 21], 1u);
        }
    }
    __syncthreads();
    for (int i = threadIdx.x; i < 2048; i += 256) {
        u32 c = bh[i];
        if (c) atomicAdd(&hist0[b * 2048 + i], c);
    }
}

// -------------------------------------------------------------------------
// Stage 2a: exact pivot P per batch via radix refinement (1 block/batch).
// Also writes output defaults.  params[b] = {P, target}.
// -------------------------------------------------------------------------
__global__ __launch_bounds__(1024) void pivot_kernel(
    const u32* __restrict__ keys, const u32* __restrict__ hist0,
    u32* __restrict__ params,
    float* __restrict__ tscore, float* __restrict__ tcls, float4* __restrict__ tbox)
{
    __shared__ u32 shist[2048];
    __shared__ u32 s_wtot[16];
    __shared__ int s_tf;
    __shared__ u32 s_C, s_above;
    int b = blockIdx.x, tid = threadIdx.x;
    int lane = tid & 63, wave = tid >> 6;
    const u32* kb = keys + (size_t)b * NTOT;

    for (int i = tid; i < TOPN; i += 1024) {
        size_t o = (size_t)b * TOPN + i;
        tscore[o] = -1.0f; tcls[o] = -1.0f;
        tbox[o] = make_float4(0.f, 0.f, 0.f, 0.f);
    }

    // ---- level 1: suffix scan of hist0 ----
    u32 h0 = hist0[b * 2048 + 2 * tid];
    u32 h1 = hist0[b * 2048 + 2 * tid + 1];
    if (tid == 0) s_tf = -1;
    u32 x = h0 + h1;
#pragma unroll
    for (int off = 1; off < 64; off <<= 1) {
        u32 y = __shfl_down(x, off);
        if (lane + off < 64) x += y;
    }
    if (lane == 0) s_wtot[wave] = x;
    __syncthreads();
    u32 wsuf = 0, tot = 0;
    for (int w2 = 0; w2 < 16; ++w2) { u32 v = s_wtot[w2]; tot += v; if (w2 > wave) wsuf += v; }
    u32 suf0 = x + wsuf, suf1 = suf0 - h0;
    u32 target = (tot < TOPN) ? tot : TOPN;

    if (target > 0) {
        if (suf0 >= target) atomicMax(&s_tf, 2 * tid);
        if (suf1 >= target) atomicMax(&s_tf, 2 * tid + 1);
    }
    __syncthreads();
    int t0 = s_tf;
    if (target > 0) {
        if (2 * tid == t0)     { s_C = suf0; s_above = suf0 - h0; }
        if (2 * tid + 1 == t0) { s_C = suf1; s_above = suf1 - h1; }
    }
    __syncthreads();
    u32 C0 = (target > 0) ? s_C : 0;
    u32 above0 = (target > 0) ? s_above : 0;

    // ---- level 2 (scan keys in bin t0) ----
    bool need2 = (target > 0 && C0 > CAP);
    int t1 = 0; u32 C1 = 0, above1 = 0;
    shist[2 * tid] = 0; shist[2 * tid + 1] = 0;
    if (tid == 0) s_tf = -1;
    __syncthreads();
    if (need2) {
        for (int i = tid; i < NTOT; i += 1024) {
            u32 k = kb[i];
            if (k && (int)(k >> 21) == t0) atomicAdd(&shist[(k >> 10) & 2047], 1u);
        }
    }
    __syncthreads();
    {
        u32 g0 = shist[2 * tid], g1 = shist[2 * tid + 1];
        u32 x2 = g0 + g1;
#pragma unroll
        for (int off = 1; off < 64; off <<= 1) {
            u32 y = __shfl_down(x2, off);
            if (lane + off < 64) x2 += y;
        }
        if (lane == 0) s_wtot[wave] = x2;
        __syncthreads();
        u32 ws2 = 0;
        for (int w2 = wave + 1; w2 < 16; ++w2) ws2 += s_wtot[w2];
        u32 sa0 = x2 + ws2, sa1 = sa0 - g0;
        u32 need2c = target - above0;
        if (need2) {
            if (sa0 >= need2c) atomicMax(&s_tf, 2 * tid);
            if (sa1 >= need2c) atomicMax(&s_tf, 2 * tid + 1);
        }
        __syncthreads();
        t1 = s_tf;
        if (need2) {
            if (2 * tid == t1)     { s_C = above0 + sa0; s_above = above0 + sa0 - g0; }
            if (2 * tid + 1 == t1) { s_C = above0 + sa1; s_above = above0 + sa1 - g1; }
        }
        __syncthreads();
        if (need2) { C1 = s_C; above1 = s_above; }
    }

    // ---- level 3 (scan keys in bin (t0,t1)) ----
    bool need3 = (need2 && C1 > CAP);
    int t2 = 0;
    __syncthreads();
    shist[2 * tid] = 0; shist[2 * tid + 1] = 0;
    if (tid == 0) s_tf = -1;
    __syncthreads();
    if (need3) {
        for (int i = tid; i < NTOT; i += 1024) {
            u32 k = kb[i];
            if (k && (int)(k >> 21) == t0 && (int)((k >> 10) & 2047) == t1)
                atomicAdd(&shist[k & 1023], 1u);
        }
    }
    __syncthreads();
    {
        u32 g = shist[tid];
        u32 x3 = g;
#pragma unroll
        for (int off = 1; off < 64; off <<= 1) {
            u32 y = __shfl_down(x3, off);
            if (lane + off < 64) x3 += y;
        }
        if (lane == 0) s_wtot[wave] = x3;
        __syncthreads();
        u32 ws3 = 0;
        for (int w2 = wave + 1; w2 < 16; ++w2) ws3 += s_wtot[w2];
        u32 sb = x3 + ws3;
        if (need3) {
            u32 need3c = target - above1;
            if (sb >= need3c && tid < 1024) atomicMax(&s_tf, tid);
        }
        __syncthreads();
        t2 = s_tf;
    }

    if (tid == 0) {
        u32 P;
        if (target == 0)      P = 0xFFFFFFFFu;
        else if (!need2)      P = (u32)t0 << 21;
        else if (!need3)      P = ((u32)t0 << 21) | ((u32)t1 << 10);
        else                  P = ((u32)t0 << 21) | ((u32)t1 << 10) | (u32)t2;
        params[2 * b] = P;
        params[2 * b + 1] = target;
    }
}

// -------------------------------------------------------------------------
// Stage 2b: gather all keys >= P into candbuf.  One global atomic per
// block; per-batch counters padded 128 B apart.
// -------------------------------------------------------------------------
__global__ __launch_bounds__(256) void gather_kernel(
    const u32* __restrict__ keys, const u32* __restrict__ params,
    u64* __restrict__ candbuf, u32* __restrict__ gcnt)
{
    __shared__ u32 s_wcnt[4];
    __shared__ u32 s_base;
    int b = blockIdx.y;
    int tid = threadIdx.x;
    int lane = tid & 63, wave = tid >> 6;
    u32 P = params[2 * b];
    int i = blockIdx.x * 256 + tid;
    u32 k = (i < NTOT) ? keys[(size_t)b * NTOT + i] : 0u;
    bool pass = (k != 0u) && (k >= P);
    u64 mask = __ballot(pass);
    if (lane == 0) s_wcnt[wave] = (u32)__popcll(mask);
    __syncthreads();
    if (tid == 0) {
        u32 tot = s_wcnt[0] + s_wcnt[1] + s_wcnt[2] + s_wcnt[3];
        s_base = tot ? atomicAdd(&gcnt[b * 32], tot) : 0u;
    }
    __syncthreads();
    if (pass) {
        u32 woff = 0;
        for (int w2 = 0; w2 < wave; ++w2) woff += s_wcnt[w2];
        u32 pos = s_base + woff + (u32)__popcll(mask & ((1ull << lane) - 1ull));
        if (pos < CAPC)
            candbuf[(size_t)b * CAPC + pos] = ((u64)k << 32) | (u32)(~i);
    }
}

// -------------------------------------------------------------------------
// Stage 2c: rank-by-count + scatter.  Box decode (reg read + trunc) is
// done here for the <= CAPC candidates only (exact same fp32 ops as the
// reference; px,py recomputed exactly).
// -------------------------------------------------------------------------
__global__ __launch_bounds__(256) void rank_kernel(
    const u64* __restrict__ candbuf, const u32* __restrict__ gcnt,
    const u32* __restrict__ params,
    const int* __restrict__ clsidx,
    const float* __restrict__ reg0, const float* __restrict__ reg1,
    const float* __restrict__ reg2, const float* __restrict__ reg3,
    const float* __restrict__ reg4,
    float* __restrict__ tscore, float* __restrict__ tcls, float4* __restrict__ tbox)
{
    int b = blockIdx.y;
    int lane = threadIdx.x & 63;
    u32 M = gcnt[b * 32]; if (M > CAPC) M = CAPC;
    u32 target = params[2 * b + 1];
    const u64* cb = candbuf + (size_t)b * CAPC;
    u32 Mr = (M + 63u) & ~63u;

    u32 wbase0 = blockIdx.x * 256 + (threadIdx.x & ~63u);
    for (u32 base = wbase0; base < M; base += 8 * 256) {   // uniform per wave
        u32 i0 = base + lane;
        bool val = (i0 < M);
        u64 e = val ? cb[i0] : ~0ull;
        u32 r = 0;
        for (u32 c0 = 0; c0 < Mr; c0 += 64) {
            u32 j = c0 + lane;
            u64 v = (j < M) ? cb[j] : 0ull;   // 0 is never > any candidate
            u32 vlo = (u32)v, vhi = (u32)(v >> 32);
#pragma unroll
            for (int s = 0; s < 64; ++s) {
                u32 lo = (u32)__builtin_amdgcn_readlane((int)vlo, s);
                u32 hi = (u32)__builtin_amdgcn_readlane((int)vhi, s);
                u64 vj = ((u64)hi << 32) | lo;
                r += (vj > e) ? 1u : 0u;
            }
        }
        if (val && r < target) {
            u32 k = (u32)(e >> 32);
            u32 loc = ~(u32)e;
            const float* rp; float st; u32 li; int wsh;
            if (loc < 16384u)      { li = loc;          wsh = 7; st = 8.f;   rp = reg0 + ((size_t)b*16384 + li)*4; }
            else if (loc < 20480u) { li = loc - 16384u; wsh = 6; st = 16.f;  rp = reg1 + ((size_t)b*4096  + li)*4; }
            else if (loc < 21504u) { li = loc - 20480u; wsh = 5; st = 32.f;  rp = reg2 + ((size_t)b*1024  + li)*4; }
            else if (loc < 21760u) { li = loc - 21504u; wsh = 4; st = 64.f;  rp = reg3 + ((size_t)b*256   + li)*4; }
            else                   { li = loc - 21760u; wsh = 3; st = 128.f; rp = reg4 + ((size_t)b*64    + li)*4; }
            u32 wx = li & ((1u << wsh) - 1u);
            u32 hy = li >> wsh;
            float px = ((float)wx + 0.5f) * st;
            float py = ((float)hy + 0.5f) * st;
            float4 rg = *(const float4*)rp;
            float4 bx;
            bx.x = truncf(px - rg.x); bx.y = truncf(py - rg.y);
            bx.z = truncf(px + rg.z); bx.w = truncf(py + rg.w);
            size_t src = (size_t)b * NTOT + loc;
            size_t o = (size_t)b * TOPN + r;
            tscore[o] = __uint_as_float(k & 0x7FFFFFFFu);
            tcls[o] = (float)clsidx[src];
            tbox[o] = bx;
        }
    }
}

// -------------------------------------------------------------------------
// Stage 3: suppression-bit matrix.  4 rows per 256-thread block.
// -------------------------------------------------------------------------
__global__ __launch_bounds__(256) void iou_kernel(
    const float4* __restrict__ tbox, u64* __restrict__ sup)
{
    __shared__ float4 sbox[TOPN];
    int b = blockIdx.y;
    int tid = threadIdx.x, lane = tid & 63, wave = tid >> 6;
    const float4* tb = tbox + (size_t)b * TOPN;
    for (int i = tid; i < TOPN; i += 256) sbox[i] = tb[i];
    __syncthreads();
    int i = blockIdx.x * 4 + wave;
    float4 bi = sbox[i];
    float areai = fmaxf((bi.z - bi.x) * (bi.w - bi.y), 0.0001f);
    u64* row = sup + ((size_t)b * TOPN + i) * 16;
#pragma unroll
    for (int w = 0; w < 16; ++w) {
        int col = w * 64 + lane;
        bool bit = false;
        if (col < TOPN) {
            float4 bj = sbox[col];
            float areaj = fmaxf((bj.z - bj.x) * (bj.w - bj.y), 0.0001f);
            float tlx = fmaxf(bi.x, bj.x), tly = fmaxf(bi.y, bj.y);
            float brx = fminf(bi.z, bj.z), bry = fminf(bi.w, bj.w);
            float ow = fmaxf(brx - tlx, 0.f), oh = fmaxf(bry - tly, 0.f);
            float inter = ow * oh;
            float uni = fmaxf(areai + areaj - inter, 0.0001f);
            bit = (col > i) && (inter / uni >= 0.6f);
        }
        u64 m = __ballot(bit);
        if (lane == 0) row[w] = m;
    }
}

// -------------------------------------------------------------------------
// Stage 4: greedy serial scan + popcount-rank output.
// -------------------------------------------------------------------------
#define CHROWS 128
#define NCHUNK 8

__global__ __launch_bounds__(1024) void finalize_kernel(
    const float* __restrict__ tscore, const float* __restrict__ tcls,
    const float4* __restrict__ tbox, const u64* __restrict__ sup,
    float* __restrict__ out)
{
    __shared__ u64 mat[2][CHROWS * 16];
    __shared__ u32 validsh[TOPN];
    __shared__ u64 removed_sh[16];
    __shared__ u32 wpref[17];
    int b = blockIdx.x, tid = threadIdx.x;
    int wave = tid >> 6, lane = tid & 63;

    for (int i = tid; i < TOPN; i += 1024)
        validsh[i] = (tscore[(size_t)b * TOPN + i] > 0.05f) ? 1u : 0u;

    const u64* supb = sup + (size_t)b * TOPN * 16;
    for (int idx = tid; idx < CHROWS * 16; idx += 1024)
        mat[0][idx] = supb[idx];
    __syncthreads();

    u64 my = 0;
    if (wave == 0) {
#pragma unroll
        for (int w2 = 0; w2 < 16; ++w2) {
            int i = w2 * 64 + lane;
            bool v = (i < TOPN) ? (validsh[i] != 0) : false;
            u64 m = __ballot(v);
            if (lane == w2) my = ~m;
        }
    }

    for (int chunk = 0; chunk < NCHUNK; ++chunk) {
        if (wave > 0 && chunk + 1 < NCHUNK) {
            int nr = (chunk + 1 == NCHUNK - 1) ? (TOPN - (NCHUNK - 1) * CHROWS) : CHROWS;
            const u64* src = supb + (size_t)(chunk + 1) * CHROWS * 16;
            u64* dst = mat[(chunk + 1) & 1];
            for (int idx = tid - 64; idx < nr * 16; idx += 960)
                dst[idx] = src[idx];
        }
        if (wave == 0) {
            int r0 = chunk * CHROWS;
            int rows = (chunk == NCHUNK - 1) ? (TOPN - r0) : CHROWS;
            int lw = lane & 15;
            const u64* M = mat[chunk & 1];
            for (int sub = 0; sub < rows; sub += 64) {
                int w2 = (r0 + sub) >> 6;
                u64 cur = __shfl(my, w2);
                int nsub = rows - sub; if (nsub > 64) nsub = 64;
                const u64* R = M + sub * 16;
                int ngrp = nsub >> 3;
                u64 cme[8], cww[8];
#pragma unroll
                for (int g = 0; g < 8; ++g) { cme[g] = R[g*16 + lw]; cww[g] = R[g*16 + w2]; }
                for (int grp = 0; grp < ngrp; ++grp) {
                    u64 nme[8] = {0,0,0,0,0,0,0,0}, nww[8] = {0,0,0,0,0,0,0,0};
                    if (grp + 1 < ngrp) {
                        const u64* Rn = R + (grp + 1) * 128;
#pragma unroll
                        for (int g = 0; g < 8; ++g) { nme[g] = Rn[g*16 + lw]; nww[g] = Rn[g*16 + w2]; }
                    }
#pragma unroll
                    for (int g = 0; g < 8; ++g) {
                        int u = grp * 8 + g;
                        u64 bit = (cur >> u) & 1ull;
                        u64 act = bit - 1ull;
                        cur |= cww[g] & act;
                        my  |= cme[g] & act;
                    }
#pragma unroll
                    for (int g = 0; g < 8; ++g) { cme[g] = nme[g]; cww[g] = nww[g]; }
                }
            }
        }
        __syncthreads();
    }
    if (wave == 0) {
        if (lane < 16) removed_sh[lane] = my;
        u32 pc = (lane < 16) ? (u32)__popcll(~my) : 0u;
#pragma unroll
        for (int off = 1; off < 16; off <<= 1) {
            u32 y = __shfl_up(pc, off);
            if (lane >= off) pc += y;
        }
        if (lane < 16) wpref[lane + 1] = pc;
        if (lane == 0) wpref[0] = 0;
    }
    __syncthreads();

    float* out_s = out;
    float* out_c = out + NBATCH * MAXOBJ;
    float* out_b = out + 2 * NBATCH * MAXOBJ;
    if (tid < MAXOBJ)     { out_s[b * MAXOBJ + tid] = -1.f; out_c[b * MAXOBJ + tid] = -1.f; }
    if (tid < MAXOBJ * 4) out_b[b * MAXOBJ * 4 + tid] = 0.f;
    __syncthreads();
    if (tid < TOPN) {
        u64 kw = ~removed_sh[tid >> 6];       // keep-word (invalid already removed)
        if ((kw >> (tid & 63)) & 1ull) {
            int rank = (int)wpref[tid >> 6] + (int)__popcll(kw & ((1ull << (tid & 63)) - 1ull));
            if (rank < MAXOBJ) {
                size_t o = (size_t)b * TOPN + tid;
                out_s[b * MAXOBJ + rank] = tscore[o];
                out_c[b * MAXOBJ + rank] = tcls[o];
                ((float4*)out_b)[b * MAXOBJ + rank] = tbox[o];
            }
        }
    }
}

// -------------------------------------------------------------------------
// Workspace layout (bytes), total 10,812,416:
//   keys    u32 [16][21824]     @ 0
//   clsidx  i32 [16][21824]     @ 1,396,736
//   (unused gap; was boxes)     @ 2,793,472
//   tscore  f32 [16][1000]      @ 8,380,416
//   tcls    f32 [16][1000]      @ 8,444,416
//   tbox    f4  [16][1000]      @ 8,508,416
//   sup     u64 [16][1000][16]  @ 8,764,416  (iou output; clobbers the below)
//   candbuf u64 [16][8192]      @ 8,764,416  (dead after rank)
//   hist0   u32 [16][2048]      @ 9,812,992  (dead after pivot)
//   gcnt    u32 [16][32] padded @ 9,944,064  (128 B per batch counter)
//   params  u32 [16][2]         @ 9,946,112
// -------------------------------------------------------------------------
extern "C" void kernel_launch(void* const* d_in, const int* in_sizes, int n_in,
                              void* d_out, int out_size, void* d_ws, size_t ws_size,
                              hipStream_t stream) {
    (void)in_sizes; (void)n_in; (void)out_size; (void)ws_size;
    const float* cls[5]; const float* reg[5]; const float* ctr[5];
    for (int l = 0; l < 5; ++l) {
        cls[l] = (const float*)d_in[4 * l + 0];
        reg[l] = (const float*)d_in[4 * l + 1];
        ctr[l] = (const float*)d_in[4 * l + 2];
    }
    char* w = (char*)d_ws;
    u32*    keys   = (u32*)(w + 0);
    int*    clsidx = (int*)(w + 1396736);
    float*  tscore = (float*)(w + 8380416);
    float*  tcls   = (float*)(w + 8444416);
    float4* tbox   = (float4*)(w + 8508416);
    u64*    sup    = (u64*)(w + 8764416);
    u64*    candbuf= (u64*)(w + 8764416);
    u32*    hist0  = (u32*)(w + 9812992);
    u32*    gcnt   = (u32*)(w + 9944064);
    u32*    params = (u32*)(w + 9946112);

    zero_kernel<<<33, 1024, 0, stream>>>(hist0);   // hist0 + padded gcnt contiguous
    decode_kernel<<<dim3((NTOT + 63) / 64, NBATCH), 256, 0, stream>>>(
        cls[0], cls[1], cls[2], cls[3], cls[4],
        ctr[0], ctr[1], ctr[2], ctr[3], ctr[4],
        keys, clsidx, hist0);
    pivot_kernel<<<NBATCH, 1024, 0, stream>>>(keys, hist0, params, tscore, tcls, tbox);
    gather_kernel<<<dim3((NTOT + 255) / 256, NBATCH), 256, 0, stream>>>(keys, params, candbuf, gcnt);
    rank_kernel<<<dim3(8, NBATCH), 256, 0, stream>>>(candbuf, gcnt, params, clsidx,
                                                     reg[0], reg[1], reg[2], reg[3], reg[4],
                                                     tscore, tcls, tbox);
    iou_kernel<<<dim3(TOPN / 4, NBATCH), 256, 0, stream>>>(tbox, sup);
    finalize_kernel<<<NBATCH, 1024, 0, stream>>>(tscore, tcls, tbox, sup, (float*)d_out);
}